// Round 9
// baseline (523.895 us; speedup 1.0000x reference)
//
#include <hip/hip_runtime.h>
#include <math.h>

typedef unsigned short u16;
typedef unsigned int u32;
typedef __attribute__((ext_vector_type(8))) short short8;   // 8 bf16 (4 VGPRs)
typedef __attribute__((ext_vector_type(4))) float f32x4;

__device__ __forceinline__ float bf2f(u16 u) {
  union { u32 i; float f; } v; v.i = ((u32)u) << 16; return v.f;
}
__device__ __forceinline__ u16 f2bf(float f) {
  union { float f; u32 i; } v; v.f = f;
  u32 i = v.i;
  i += 0x7fffu + ((i >> 16) & 1u);   // round-to-nearest-even
  return (u16)(i >> 16);
}

// dtype-polymorphic loads (F32: inputs are float32; else bf16 bits)
template<bool F32>
__device__ __forceinline__ float ld(const void* p, int i) {
  if (F32) return ((const float*)p)[i];
  return bf2f(((const u16*)p)[i]);
}

// ---------------------------------------------------------------------------
// Kernel 0: detect input dtype (fp32 vs bf16-packed).
// ---------------------------------------------------------------------------
__global__ __launch_bounds__(64)
void detect_kernel(const void* __restrict__ xv, int* __restrict__ flag) {
  const u32* xw = (const u32*)xv;
  const int t = threadIdx.x;
  int bad = 0;
  for (int i = t; i < 1024; i += 64) {
    const int e = (int)((xw[i] >> 7) & 0xFF);
    if (e < 90 || e > 150) bad++;
  }
#pragma unroll
  for (int m = 1; m < 64; m <<= 1) bad += __shfl_xor(bad, m);
  if (t == 0) *flag = (bad > 256) ? 1 : 0;
}

// ---------------------------------------------------------------------------
// Token-major shifted gather: lane (s, cg) loads token s's channels cg*8..+7
// of window (wbase + w) as two 16B loads (8 lanes cover a 256B row).
// ---------------------------------------------------------------------------
template<bool F32>
__device__ __forceinline__ void gather8(const void* __restrict__ x, int chunk,
                                        int w, int s, int cg, float* pf) {
  const int b     = chunk >> 13;
  const int wbase = (chunk & 8191) << 2;
  const int widx  = wbase + w;
  const int wz = widx >> 10, wy = (widx >> 5) & 31, wx = widx & 31;
  const int od = (2*wz + ((s>>2)&1) + 1) & 63;
  const int oh = (2*wy + ((s>>1)&1) + 1) & 63;
  const int ow = (2*wx + ( s    &1) + 1) & 63;
  const int base = (((b<<18) + ((od<<12)|(oh<<6)|ow)) << 6) + cg*8;
  if (F32) {
    const f32x4 a = *(const f32x4*)((const float*)x + base);
    const f32x4 c = *(const f32x4*)((const float*)x + base + 4);
    pf[0]=a[0]; pf[1]=a[1]; pf[2]=a[2]; pf[3]=a[3];
    pf[4]=c[0]; pf[5]=c[1]; pf[6]=c[2]; pf[7]=c[3];
  } else {
    const short8 a = *(const short8*)((const u16*)x + base);
#pragma unroll
    for (int j = 0; j < 8; ++j) pf[j] = bf2f((u16)a[j]);
  }
}

// bug-faithful window-reverse scatter base for token tok of chunk's windows
__device__ __forceinline__ int scat(int chunk, int tok) {
  const int b     = chunk >> 13;
  const int wbase = (chunk & 8191) << 2;
  const int widx = wbase + (tok >> 3);
  const int s    = tok & 7;
  const int wz = widx >> 10, wy = (widx >> 5) & 31, wx = widx & 31;
  const int fd = (2*wz + ((wy>>3)&1) + 1) & 63;
  const int Hb = 8*(wy&7) + 4*(wx>>4) + (wy>>4);
  const int Wb = 4*(wx&15);
  const int i = (s>>2)&1, j = (s>>1)&1, k = s&1;
  const int fh = (Hb + 2*j + 1) & 63;
  const int fw = (Wb + 2*i + k + 1) & 63;
  return ((b<<18) + ((fd<<12)|(fh<<6)|fw)) << 6;
}

template<bool F32>
__device__ __forceinline__ void loadx8(const void* __restrict__ x, int base,
                                       float* xr) {
  if (F32) {
    const f32x4 a = *(const f32x4*)((const float*)x + base);
    const f32x4 c = *(const f32x4*)((const float*)x + base + 4);
    xr[0]=a[0]; xr[1]=a[1]; xr[2]=a[2]; xr[3]=a[3];
    xr[4]=c[0]; xr[5]=c[1]; xr[6]=c[2]; xr[7]=c[3];
  } else {
    const short8 a = *(const short8*)((const u16*)x + base);
#pragma unroll
    for (int j = 0; j < 8; ++j) xr[j] = bf2f((u16)a[j]);
  }
}

#define MFMA __builtin_amdgcn_mfma_f32_16x16x32_bf16

// ===========================================================================
// PATH B (workspace >= 64MB): attnB writes attnout bf16 token-linear to ws;
// mlpB adds residual x[scat], does LN2+MLP, writes out[scat].
// ALL global stores are full-line token-major (fixes write-allocate RMW).
// ===========================================================================

// ---------------------------------------------------------------------------
// attnB: LN1 + window attention + proj(+pb) -> ws (bf16, token order, LINEAR).
// bf16 q/k/v LDS (18.4 KB -> 8 blocks/CU). Store bounced through LDS so one
// wave's 8 lanes emit a full 128B bf16 row (16B per lane).
// ---------------------------------------------------------------------------
template<bool F32>
__device__ __forceinline__ void attnB_body(
    const void* __restrict__ x,
    const void* __restrict__ n1g, const void* __restrict__ n1b,
    const void* __restrict__ qkvw, const void* __restrict__ qkvb,
    const void* __restrict__ rpb,
    const void* __restrict__ projw, const void* __restrict__ projb,
    u16* __restrict__ wsout,
    u16* __restrict__ aL, u16* __restrict__ qL,
    u16* __restrict__ kL, u16* __restrict__ vL)
{
  const int tid  = threadIdx.x;
  const int w    = tid >> 6, l = tid & 63;
  const int quad = l >> 4,  col = l & 15;
  const int s8   = l >> 3,  cg  = l & 7;   // token-major split (= head, query)

  float g1v[8], be1v[8];
#pragma unroll
  for (int j = 0; j < 8; ++j) {
    g1v[j]  = ld<F32>(n1g, cg*8 + j);
    be1v[j] = ld<F32>(n1b, cg*8 + j);
  }

  // ---- register-resident weight fragments (once per block) ----
  short8 bq[3][2];
#pragma unroll
  for (int nt = 0; nt < 3; ++nt)
#pragma unroll
    for (int kt = 0; kt < 2; ++kt) {
      short8 f;
#pragma unroll
      for (int j = 0; j < 8; ++j)
        f[j] = (short)f2bf(ld<F32>(qkvw, (kt*32 + quad*8 + j)*192 + w*48 + nt*16 + col));
      bq[nt][kt] = f;
    }
  float qb[3];
#pragma unroll
  for (int nt = 0; nt < 3; ++nt) qb[nt] = ld<F32>(qkvb, w*48 + nt*16 + col);
  short8 bp[2];
#pragma unroll
  for (int kt = 0; kt < 2; ++kt) {
    short8 f;
#pragma unroll
    for (int j = 0; j < 8; ++j)
      f[j] = (short)f2bf(ld<F32>(projw, (kt*32 + quad*8 + j)*64 + w*16 + col));
    bp[kt] = f;
  }
  const float pbv = ld<F32>(projb, w*16 + col);
  const int rel = 3 * (((s8>>1)&1) - ((cg>>1)&1) + 1)
                +     (((s8>>2)&1) - ((cg>>2)&1) + 1)
                +     (( s8    &1) - ( cg    &1) + 1);
  float rpv[8];
#pragma unroll
  for (int kk = 0; kk < 8; ++kk) rpv[kk] = ld<F32>(rpb, rel*8 + kk);

  float pf[8];
  gather8<F32>(x, blockIdx.x, w, s8, cg, pf);   // prologue prefetch

  for (int chunk = blockIdx.x; chunk < 16384; chunk += 2048) {
    const int wbase = (chunk & 8191) << 2;
    const int widx0 = wbase + w;
    const int wz0 = widx0 >> 10, wy0 = (widx0 >> 5) & 31, wx0 = widx0 & 31;

    // ---- P0: LN1 token-major group reduce -> aL bf16 ----
    {
      float s1 = 0.f, sq = 0.f;
#pragma unroll
      for (int j = 0; j < 8; ++j) { s1 += pf[j]; sq += pf[j]*pf[j]; }
#pragma unroll
      for (int m = 1; m < 8; m <<= 1) {
        s1 += __shfl_xor(s1, m);
        sq += __shfl_xor(sq, m);
      }
      const float mu  = s1 * 0.015625f;
      const float var = sq * 0.015625f - mu * mu;
      const float rs  = rsqrtf(var + 1e-5f);
      short8 av;
#pragma unroll
      for (int j = 0; j < 8; ++j)
        av[j] = (short)f2bf((pf[j] - mu) * rs * g1v[j] + be1v[j]);
      *(short8*)&aL[(w*8 + s8)*72 + cg*8] = av;
    }
    if (chunk + 2048 < 16384) gather8<F32>(x, chunk + 2048, w, s8, cg, pf);
    __syncthreads();                                       // B1: aL ready

    // ---- P1: QKV MFMA -> q/k/v bf16 LDS ----
    {
      short8 aF[2][2];
#pragma unroll
      for (int mt = 0; mt < 2; ++mt)
#pragma unroll
        for (int kt = 0; kt < 2; ++kt)
          aF[mt][kt] = *(const short8*)&aL[(mt*16 + col)*72 + kt*32 + quad*8];
#pragma unroll
      for (int nt = 0; nt < 3; ++nt) {
        f32x4 a0 = (f32x4){0.f,0.f,0.f,0.f}, a1 = (f32x4){0.f,0.f,0.f,0.f};
        a0 = MFMA(aF[0][0], bq[nt][0], a0, 0, 0, 0);
        a0 = MFMA(aF[0][1], bq[nt][1], a0, 0, 0, 0);
        a1 = MFMA(aF[1][0], bq[nt][0], a1, 0, 0, 0);
        a1 = MFMA(aF[1][1], bq[nt][1], a1, 0, 0, 0);
        const int nb  = w*48 + nt*16;
        u16* dst      = (nb < 64) ? qL : (nb < 128) ? kL : vL;
        const int chb = (nb & 63) + col;
        const float scl = (nb < 64) ? 0.35355339059327373f : 1.0f;
        const float bb  = qb[nt];
#pragma unroll
        for (int r = 0; r < 4; ++r) {
          dst[(quad*4 + r)*72 + chb]      = f2bf((a0[r] + bb) * scl);
          dst[(16 + quad*4 + r)*72 + chb] = f2bf((a1[r] + bb) * scl);
        }
      }
    }
    __syncthreads();                                       // B2: q/k/v ready

    // ---- P2: softmax for window w (lane = (head s8, query cg)) ----
    {
      const int tq = w*8 + cg;
      float qr[8];
      {
        const short8 qv = *(const short8*)&qL[tq*72 + s8*8];
#pragma unroll
        for (int d = 0; d < 8; ++d) qr[d] = bf2f((u16)qv[d]);
      }
      float sc8[8];
#pragma unroll
      for (int kk = 0; kk < 8; ++kk) {
        const short8 kv = *(const short8*)&kL[(w*8 + kk)*72 + s8*8];
        float a = 0.f;
#pragma unroll
        for (int d = 0; d < 8; ++d) a += qr[d] * bf2f((u16)kv[d]);
        sc8[kk] = a + rpv[kk];
      }
      if ((wz0 == 31) || (wy0 == 31) || (wx0 == 31)) {   // boundary only; exact
        int cnts[8];
#pragma unroll
        for (int p = 0; p < 8; ++p) {
          const int sd = 2*wz0 + ((p>>2)&1);
          const int sh = 2*wy0 + ((p>>1)&1);
          const int sw = 2*wx0 + (p&1);
          cnts[p] = (sd >= 62 ? sd - 61 : 0)*9 + (sh >= 62 ? sh - 61 : 0)*3
                  + (sw >= 62 ? sw - 61 : 0);
        }
#pragma unroll
        for (int kk = 0; kk < 8; ++kk)
          if (cnts[kk] != cnts[cg]) sc8[kk] -= 100.f;
      }
      float mx = sc8[0];
#pragma unroll
      for (int kk = 1; kk < 8; ++kk) mx = fmaxf(mx, sc8[kk]);
      float pr[8], lsum = 0.f;
#pragma unroll
      for (int kk = 0; kk < 8; ++kk) { pr[kk] = __expf(sc8[kk] - mx); lsum += pr[kk]; }
      const float inv = __builtin_amdgcn_rcpf(lsum);
      float o[8];
#pragma unroll
      for (int d = 0; d < 8; ++d) o[d] = 0.f;
#pragma unroll
      for (int kk = 0; kk < 8; ++kk) {
        const short8 vv = *(const short8*)&vL[(w*8 + kk)*72 + s8*8];
#pragma unroll
        for (int d = 0; d < 8; ++d) o[d] += pr[kk] * bf2f((u16)vv[d]);
      }
      short8 ov;
#pragma unroll
      for (int d = 0; d < 8; ++d) ov[d] = (short)f2bf(o[d] * inv);
      *(short8*)&qL[tq*72 + s8*8] = ov;    // O into own q-slot (lane-private)
    }
    __syncthreads();                                       // B3: O ready

    // ---- P3: proj MFMA (A = O from qL) -> bf16 result into vL (dead) ----
    {
      f32x4 c0 = (f32x4){0.f,0.f,0.f,0.f}, c1 = (f32x4){0.f,0.f,0.f,0.f};
      c0 = MFMA(*(const short8*)&qL[(col)*72 + quad*8],         bp[0], c0, 0, 0, 0);
      c0 = MFMA(*(const short8*)&qL[(col)*72 + 32 + quad*8],    bp[1], c0, 0, 0, 0);
      c1 = MFMA(*(const short8*)&qL[(16+col)*72 + quad*8],      bp[0], c1, 0, 0, 0);
      c1 = MFMA(*(const short8*)&qL[(16+col)*72 + 32 + quad*8], bp[1], c1, 0, 0, 0);
#pragma unroll
      for (int r = 0; r < 4; ++r) {
        vL[(quad*4 + r)*72 + w*16 + col]      = f2bf(c0[r] + pbv);
        vL[(16 + quad*4 + r)*72 + w*16 + col] = f2bf(c1[r] + pbv);
      }
    }
    __syncthreads();                                       // B4: result staged

    // ---- P3b: token-major FULL-LINE store to ws (16B/lane, 128B/row) ----
    {
      const int tok_l = w*8 + s8;
      const short8 ov = *(const short8*)&vL[tok_l*72 + cg*8];
      *(short8*)&wsout[((chunk << 5) + tok_l)*64 + cg*8] = ov;
    }
    // next P0 writes aL (last read in P1, fenced by B2/B3/B4); next P1
    // writes qL/kL/vL after B1, fencing P3/P3b reads of this chunk.
  }
}

__global__ __launch_bounds__(256, 4)
void attnB_kernel(const void* __restrict__ x,
                  const void* __restrict__ n1g, const void* __restrict__ n1b,
                  const void* __restrict__ qkvw, const void* __restrict__ qkvb,
                  const void* __restrict__ rpb,
                  const void* __restrict__ projw, const void* __restrict__ projb,
                  const int* __restrict__ flag, u16* __restrict__ wsout)
{
  __shared__ __align__(16) u16 aL[32*72];   // 4.6 KB
  __shared__ __align__(16) u16 qL[32*72];   // 4.6 KB (q, then O)
  __shared__ __align__(16) u16 kL[32*72];   // 4.6 KB
  __shared__ __align__(16) u16 vL[32*72];   // 4.6 KB (v, then proj result)
  if (*flag)
    attnB_body<true >(x, n1g, n1b, qkvw, qkvb, rpb, projw, projb, wsout, aL, qL, kL, vL);
  else
    attnB_body<false>(x, n1g, n1b, qkvw, qkvb, rpb, projw, projb, wsout, aL, qL, kL, vL);
}

// ---------------------------------------------------------------------------
// mlpB: y = x[scat] + attnout(ws, linear) ; LN2 + MLP ; out[scat] = y + mlp.
// Final store token-major full-line (two f32x4 per lane = 256B per row from
// one wave). mlp-branch output bounced through aL as bf16.
// ---------------------------------------------------------------------------
template<bool F32>
__device__ __forceinline__ void mlpB_body(
    const void* __restrict__ x, const u16* __restrict__ wsattn,
    float* __restrict__ out,
    const void* __restrict__ n2g, const void* __restrict__ n2b,
    const void* __restrict__ mw1, const void* __restrict__ mb1,
    const void* __restrict__ mw2, const void* __restrict__ mb2,
    u16* __restrict__ aL, u16* __restrict__ hL, float* __restrict__ yL)
{
  const int tid  = threadIdx.x;
  const int w    = tid >> 6, l = tid & 63;
  const int quad = l >> 4,  col = l & 15;
  const int s8   = l >> 3,  cg  = l & 7;
  const int tok_l = w*8 + s8;

  float g2v[8], be2v[8];
#pragma unroll
  for (int j = 0; j < 8; ++j) {
    g2v[j]  = ld<F32>(n2g, cg*8 + j);
    be2v[j] = ld<F32>(n2b, cg*8 + j);
  }

  short8 b1f[2][4];
#pragma unroll
  for (int kt = 0; kt < 2; ++kt)
#pragma unroll
    for (int nt = 0; nt < 4; ++nt) {
      short8 f;
#pragma unroll
      for (int j = 0; j < 8; ++j)
        f[j] = (short)f2bf(ld<F32>(mw1, (kt*32 + quad*8 + j)*256 + w*64 + nt*16 + col));
      b1f[kt][nt] = f;
    }
  short8 b2f[8];
#pragma unroll
  for (int kt = 0; kt < 8; ++kt) {
    short8 f;
#pragma unroll
    for (int j = 0; j < 8; ++j)
      f[j] = (short)f2bf(ld<F32>(mw2, (kt*32 + quad*8 + j)*64 + w*16 + col));
    b2f[kt] = f;
  }
  float b1vv[4];
#pragma unroll
  for (int nt = 0; nt < 4; ++nt) b1vv[nt] = ld<F32>(mb1, w*64 + nt*16 + col);
  const float b2vv = ld<F32>(mb2, w*16 + col);

  // prologue prefetch: residual x (scattered, token-major) + attnout (linear)
  float xr[8]; short8 ao;
  int off_c = scat(blockIdx.x, tok_l);
  loadx8<F32>(x, off_c + cg*8, xr);
  ao = *(const short8*)&wsattn[((blockIdx.x << 5) + tok_l)*64 + cg*8];

  for (int chunk = blockIdx.x; chunk < 16384; chunk += 2048) {
    // ---- P0: y = x + attnout ; LN2 group reduce ; stash y ----
    {
      float yv[8];
#pragma unroll
      for (int j = 0; j < 8; ++j) yv[j] = xr[j] + bf2f((u16)ao[j]);
      float s1 = 0.f, sq = 0.f;
#pragma unroll
      for (int j = 0; j < 8; ++j) { s1 += yv[j]; sq += yv[j]*yv[j]; }
#pragma unroll
      for (int m = 1; m < 8; m <<= 1) {
        s1 += __shfl_xor(s1, m);
        sq += __shfl_xor(sq, m);
      }
      const float mu  = s1 * 0.015625f;
      const float var = sq * 0.015625f - mu * mu;
      const float rs  = rsqrtf(var + 1e-5f);
      short8 av;
#pragma unroll
      for (int j = 0; j < 8; ++j)
        av[j] = (short)f2bf((yv[j] - mu) * rs * g2v[j] + be2v[j]);
      *(short8*)&aL[tok_l*72 + cg*8] = av;
      *(f32x4*)&yL[tok_l*68 + cg*8]     = (f32x4){yv[0], yv[1], yv[2], yv[3]};
      *(f32x4*)&yL[tok_l*68 + cg*8 + 4] = (f32x4){yv[4], yv[5], yv[6], yv[7]};
    }
    int off_n = off_c;
    if (chunk + 2048 < 16384) {   // cross-chunk prefetch
      off_n = scat(chunk + 2048, tok_l);
      loadx8<F32>(x, off_n + cg*8, xr);
      ao = *(const short8*)&wsattn[(((chunk + 2048) << 5) + tok_l)*64 + cg*8];
    }
    __syncthreads();                                       // B1: aL/yL ready

    // ---- P1: GEMM1 (32x64 @ 64x256) + tanh-GELU -> hL ----
    {
      short8 aF[2][2];
#pragma unroll
      for (int mt = 0; mt < 2; ++mt)
#pragma unroll
        for (int kt = 0; kt < 2; ++kt)
          aF[mt][kt] = *(const short8*)&aL[(mt*16 + col)*72 + kt*32 + quad*8];
#pragma unroll
      for (int nt = 0; nt < 4; ++nt) {
        f32x4 m0 = (f32x4){0.f,0.f,0.f,0.f}, m1 = (f32x4){0.f,0.f,0.f,0.f};
        m0 = MFMA(aF[0][0], b1f[0][nt], m0, 0, 0, 0);
        m0 = MFMA(aF[0][1], b1f[1][nt], m0, 0, 0, 0);
        m1 = MFMA(aF[1][0], b1f[0][nt], m1, 0, 0, 0);
        m1 = MFMA(aF[1][1], b1f[1][nt], m1, 0, 0, 0);
        const float bb = b1vv[nt];
#pragma unroll
        for (int r = 0; r < 4; ++r) {
          {
            const float h = m0[r] + bb;
            const float u = h * (1.5957691216f + 0.0713548162f * (h * h));
            const float e = __expf(u);
            hL[(quad*4 + r)*264 + w*64 + nt*16 + col] =
                f2bf(h - h * __builtin_amdgcn_rcpf(e + 1.f));
          }
          {
            const float h = m1[r] + bb;
            const float u = h * (1.5957691216f + 0.0713548162f * (h * h));
            const float e = __expf(u);
            hL[(16 + quad*4 + r)*264 + w*64 + nt*16 + col] =
                f2bf(h - h * __builtin_amdgcn_rcpf(e + 1.f));
          }
        }
      }
    }
    __syncthreads();                                       // B2: hL ready

    // ---- P2: GEMM2 (32x256 @ 256x64) -> bf16(mlp+b2) into aL (dead) ----
    {
      f32x4 o0 = (f32x4){0.f,0.f,0.f,0.f}, o1 = (f32x4){0.f,0.f,0.f,0.f};
#pragma unroll
      for (int kt = 0; kt < 8; ++kt) {
        o0 = MFMA(*(const short8*)&hL[(col)*264 + kt*32 + quad*8],    b2f[kt], o0, 0, 0, 0);
        o1 = MFMA(*(const short8*)&hL[(16+col)*264 + kt*32 + quad*8], b2f[kt], o1, 0, 0, 0);
      }
#pragma unroll
      for (int r = 0; r < 4; ++r) {
        aL[(quad*4 + r)*72 + w*16 + col]      = f2bf(o0[r] + b2vv);
        aL[(16 + quad*4 + r)*72 + w*16 + col] = f2bf(o1[r] + b2vv);
      }
    }
    __syncthreads();                                       // B3: mlp staged

    // ---- P2b: token-major FULL-LINE store: out = y + mlp (32B/lane) ----
    {
      const f32x4 ya = *(const f32x4*)&yL[tok_l*68 + cg*8];
      const f32x4 yb = *(const f32x4*)&yL[tok_l*68 + cg*8 + 4];
      const short8 ov = *(const short8*)&aL[tok_l*72 + cg*8];
      f32x4 sa, sb;
#pragma unroll
      for (int j = 0; j < 4; ++j) {
        sa[j] = ya[j] + bf2f((u16)ov[j]);
        sb[j] = yb[j] + bf2f((u16)ov[4 + j]);
      }
      *(f32x4*)&out[off_c + cg*8]     = sa;
      *(f32x4*)&out[off_c + cg*8 + 4] = sb;
    }
    __syncthreads();   // B4: fence aL/yL reads vs next chunk's P0 writes
    off_c = off_n;
  }
}

__global__ __launch_bounds__(256, 4)
void mlpB_kernel(const void* __restrict__ x, const u16* __restrict__ wsattn,
                 float* __restrict__ out,
                 const void* __restrict__ n2g, const void* __restrict__ n2b,
                 const void* __restrict__ mw1, const void* __restrict__ mb1,
                 const void* __restrict__ mw2, const void* __restrict__ mb2,
                 const int* __restrict__ flag)
{
  __shared__ __align__(16) u16   aL[32 * 72];    //  4.6 KB (LN2 out, then mlp)
  __shared__ __align__(16) u16   hL[32 * 264];   // 16.9 KB
  __shared__ __align__(16) float yL[32 * 68];    //  8.7 KB  (30.2 KB total)
  if (*flag)
    mlpB_body<true >(x, wsattn, out, n2g, n2b, mw1, mb1, mw2, mb2, aL, hL, yL);
  else
    mlpB_body<false>(x, wsattn, out, n2g, n2b, mw1, mb1, mw2, mb2, aL, hL, yL);
}

// ===========================================================================
// PATH A (fallback, small workspace): verified round-4 two-kernel pair.
// ===========================================================================
template<bool F32>
__device__ __forceinline__ void attnA_body(
    const void* __restrict__ x,
    const void* __restrict__ n1g, const void* __restrict__ n1b,
    const void* __restrict__ qkvw, const void* __restrict__ qkvb,
    const void* __restrict__ rpb,
    const void* __restrict__ projw, const void* __restrict__ projb,
    float* __restrict__ out,
    u16* __restrict__ aL, u16* __restrict__ qL,
    u16* __restrict__ kL, u16* __restrict__ vL)
{
  const int tid  = threadIdx.x;
  const int w    = tid >> 6, l = tid & 63;
  const int quad = l >> 4,  col = l & 15;
  const int s8   = l >> 3,  cg  = l & 7;

  float g1v[8], be1v[8];
#pragma unroll
  for (int j = 0; j < 8; ++j) {
    g1v[j]  = ld<F32>(n1g, cg*8 + j);
    be1v[j] = ld<F32>(n1b, cg*8 + j);
  }
  short8 bq[3][2];
#pragma unroll
  for (int nt = 0; nt < 3; ++nt)
#pragma unroll
    for (int kt = 0; kt < 2; ++kt) {
      short8 f;
#pragma unroll
      for (int j = 0; j < 8; ++j)
        f[j] = (short)f2bf(ld<F32>(qkvw, (kt*32 + quad*8 + j)*192 + w*48 + nt*16 + col));
      bq[nt][kt] = f;
    }
  float qb[3];
#pragma unroll
  for (int nt = 0; nt < 3; ++nt) qb[nt] = ld<F32>(qkvb, w*48 + nt*16 + col);
  short8 bp[2];
#pragma unroll
  for (int kt = 0; kt < 2; ++kt) {
    short8 f;
#pragma unroll
    for (int j = 0; j < 8; ++j)
      f[j] = (short)f2bf(ld<F32>(projw, (kt*32 + quad*8 + j)*64 + w*16 + col));
    bp[kt] = f;
  }
  const float pbv = ld<F32>(projb, w*16 + col);
  const int rel = 3 * (((s8>>1)&1) - ((cg>>1)&1) + 1)
                +     (((s8>>2)&1) - ((cg>>2)&1) + 1)
                +     (( s8    &1) - ( cg    &1) + 1);
  float rpv[8];
#pragma unroll
  for (int kk = 0; kk < 8; ++kk) rpv[kk] = ld<F32>(rpb, rel*8 + kk);

  float pf[8];
  gather8<F32>(x, blockIdx.x, w, s8, cg, pf);

  for (int chunk = blockIdx.x; chunk < 16384; chunk += 2048) {
    const int wbase = (chunk & 8191) << 2;
    const int widx0 = wbase + w;
    const int wz0 = widx0 >> 10, wy0 = (widx0 >> 5) & 31, wx0 = widx0 & 31;
    {
      float s1 = 0.f, sq = 0.f;
#pragma unroll
      for (int j = 0; j < 8; ++j) { s1 += pf[j]; sq += pf[j]*pf[j]; }
#pragma unroll
      for (int m = 1; m < 8; m <<= 1) {
        s1 += __shfl_xor(s1, m);
        sq += __shfl_xor(sq, m);
      }
      const float mu  = s1 * 0.015625f;
      const float var = sq * 0.015625f - mu * mu;
      const float rs  = rsqrtf(var + 1e-5f);
      short8 av;
#pragma unroll
      for (int j = 0; j < 8; ++j)
        av[j] = (short)f2bf((pf[j] - mu) * rs * g1v[j] + be1v[j]);
      *(short8*)&aL[(w*8 + s8)*72 + cg*8] = av;
    }
    if (chunk + 2048 < 16384) gather8<F32>(x, chunk + 2048, w, s8, cg, pf);
    __syncthreads();
    {
      short8 aF[2][2];
#pragma unroll
      for (int mt = 0; mt < 2; ++mt)
#pragma unroll
        for (int kt = 0; kt < 2; ++kt)
          aF[mt][kt] = *(const short8*)&aL[(mt*16 + col)*72 + kt*32 + quad*8];
#pragma unroll
      for (int nt = 0; nt < 3; ++nt) {
        f32x4 a0 = (f32x4){0.f,0.f,0.f,0.f}, a1 = (f32x4){0.f,0.f,0.f,0.f};
        a0 = MFMA(aF[0][0], bq[nt][0], a0, 0, 0, 0);
        a0 = MFMA(aF[0][1], bq[nt][1], a0, 0, 0, 0);
        a1 = MFMA(aF[1][0], bq[nt][0], a1, 0, 0, 0);
        a1 = MFMA(aF[1][1], bq[nt][1], a1, 0, 0, 0);
        const int nb  = w*48 + nt*16;
        u16* dst      = (nb < 64) ? qL : (nb < 128) ? kL : vL;
        const int chb = (nb & 63) + col;
        const float scl = (nb < 64) ? 0.35355339059327373f : 1.0f;
        const float bb  = qb[nt];
#pragma unroll
        for (int r = 0; r < 4; ++r) {
          dst[(quad*4 + r)*72 + chb]      = f2bf((a0[r] + bb) * scl);
          dst[(16 + quad*4 + r)*72 + chb] = f2bf((a1[r] + bb) * scl);
        }
      }
    }
    __syncthreads();
    {
      const int tq = w*8 + cg;
      float qr[8];
      {
        const short8 qv = *(const short8*)&qL[tq*72 + s8*8];
#pragma unroll
        for (int d = 0; d < 8; ++d) qr[d] = bf2f((u16)qv[d]);
      }
      float sc8[8];
#pragma unroll
      for (int kk = 0; kk < 8; ++kk) {
        const short8 kv = *(const short8*)&kL[(w*8 + kk)*72 + s8*8];
        float a = 0.f;
#pragma unroll
        for (int d = 0; d < 8; ++d) a += qr[d] * bf2f((u16)kv[d]);
        sc8[kk] = a + rpv[kk];
      }
      {
        int cnts[8];
#pragma unroll
        for (int p = 0; p < 8; ++p) {
          const int sd = 2*wz0 + ((p>>2)&1);
          const int sh = 2*wy0 + ((p>>1)&1);
          const int sw = 2*wx0 + (p&1);
          cnts[p] = (sd >= 62 ? sd - 61 : 0)*9 + (sh >= 62 ? sh - 61 : 0)*3
                  + (sw >= 62 ? sw - 61 : 0);
        }
#pragma unroll
        for (int kk = 0; kk < 8; ++kk)
          if (cnts[kk] != cnts[cg]) sc8[kk] -= 100.f;
      }
      float mx = sc8[0];
#pragma unroll
      for (int kk = 1; kk < 8; ++kk) mx = fmaxf(mx, sc8[kk]);
      float pr[8], lsum = 0.f;
#pragma unroll
      for (int kk = 0; kk < 8; ++kk) { pr[kk] = __expf(sc8[kk] - mx); lsum += pr[kk]; }
      const float inv = __builtin_amdgcn_rcpf(lsum);
      float o[8];
#pragma unroll
      for (int d = 0; d < 8; ++d) o[d] = 0.f;
#pragma unroll
      for (int kk = 0; kk < 8; ++kk) {
        const short8 vv = *(const short8*)&vL[(w*8 + kk)*72 + s8*8];
#pragma unroll
        for (int d = 0; d < 8; ++d) o[d] += pr[kk] * bf2f((u16)vv[d]);
      }
      short8 ov;
#pragma unroll
      for (int d = 0; d < 8; ++d) ov[d] = (short)f2bf(o[d] * inv);
      *(short8*)&qL[tq*72 + s8*8] = ov;
    }
    int offs[8]; float xr[8];
#pragma unroll
    for (int mt = 0; mt < 2; ++mt)
#pragma unroll
      for (int r = 0; r < 4; ++r) {
        const int off = scat(chunk, mt*16 + quad*4 + r) + w*16 + col;
        offs[mt*4 + r] = off;
        xr[mt*4 + r]   = ld<F32>(x, off);
      }
    __syncthreads();
    {
      f32x4 c0 = (f32x4){0.f,0.f,0.f,0.f}, c1 = (f32x4){0.f,0.f,0.f,0.f};
      c0 = MFMA(*(const short8*)&qL[(col)*72 + quad*8],         bp[0], c0, 0, 0, 0);
      c0 = MFMA(*(const short8*)&qL[(col)*72 + 32 + quad*8],    bp[1], c0, 0, 0, 0);
      c1 = MFMA(*(const short8*)&qL[(16+col)*72 + quad*8],      bp[0], c1, 0, 0, 0);
      c1 = MFMA(*(const short8*)&qL[(16+col)*72 + 32 + quad*8], bp[1], c1, 0, 0, 0);
#pragma unroll
      for (int r = 0; r < 4; ++r) {
        out[offs[r]]     = xr[r]     + c0[r] + pbv;
        out[offs[4 + r]] = xr[4 + r] + c1[r] + pbv;
      }
    }
    __syncthreads();
  }
}

__global__ __launch_bounds__(256, 4)
void attnA_kernel(const void* __restrict__ x,
                  const void* __restrict__ n1g, const void* __restrict__ n1b,
                  const void* __restrict__ qkvw, const void* __restrict__ qkvb,
                  const void* __restrict__ rpb,
                  const void* __restrict__ projw, const void* __restrict__ projb,
                  const int* __restrict__ flag, float* __restrict__ out)
{
  __shared__ __align__(16) u16 aL[32*72];
  __shared__ __align__(16) u16 qL[32*72];
  __shared__ __align__(16) u16 kL[32*72];
  __shared__ __align__(16) u16 vL[32*72];
  if (*flag)
    attnA_body<true >(x, n1g, n1b, qkvw, qkvb, rpb, projw, projb, out, aL, qL, kL, vL);
  else
    attnA_body<false>(x, n1g, n1b, qkvw, qkvb, rpb, projw, projb, out, aL, qL, kL, vL);
}

template<bool F32>
__device__ __forceinline__ void mlpA_body(
    float* __restrict__ io,
    const void* __restrict__ n2g, const void* __restrict__ n2b,
    const void* __restrict__ mw1, const void* __restrict__ mb1,
    const void* __restrict__ mw2, const void* __restrict__ mb2,
    u16* __restrict__ aL, u16* __restrict__ hL, float* __restrict__ yL)
{
  const int tid  = threadIdx.x;
  const int w    = tid >> 6, l = tid & 63;
  const int quad = l >> 4,  col = l & 15;
  const int s8   = l >> 3,  cg  = l & 7;
  const int ltok = w*8 + s8;

  float g2v[8], be2v[8];
#pragma unroll
  for (int j = 0; j < 8; ++j) {
    g2v[j]  = ld<F32>(n2g, cg*8 + j);
    be2v[j] = ld<F32>(n2b, cg*8 + j);
  }
  short8 b1f[2][4];
#pragma unroll
  for (int kt = 0; kt < 2; ++kt)
#pragma unroll
    for (int nt = 0; nt < 4; ++nt) {
      short8 f;
#pragma unroll
      for (int j = 0; j < 8; ++j)
        f[j] = (short)f2bf(ld<F32>(mw1, (kt*32 + quad*8 + j)*256 + w*64 + nt*16 + col));
      b1f[kt][nt] = f;
    }
  short8 b2f[8];
#pragma unroll
  for (int kt = 0; kt < 8; ++kt) {
    short8 f;
#pragma unroll
    for (int j = 0; j < 8; ++j)
      f[j] = (short)f2bf(ld<F32>(mw2, (kt*32 + quad*8 + j)*64 + w*16 + col));
    b2f[kt] = f;
  }
  float b1vv[4];
#pragma unroll
  for (int nt = 0; nt < 4; ++nt) b1vv[nt] = ld<F32>(mb1, w*64 + nt*16 + col);
  const float b2vv = ld<F32>(mb2, w*16 + col);

  float pf[8];
  {
    const float* p = &io[(blockIdx.x*32 + ltok)*64 + cg*8];
    const f32x4 a = *(const f32x4*)p;
    const f32x4 c = *(const f32x4*)(p + 4);
    pf[0]=a[0]; pf[1]=a[1]; pf[2]=a[2]; pf[3]=a[3];
    pf[4]=c[0]; pf[5]=c[1]; pf[6]=c[2]; pf[7]=c[3];
  }

  for (int chunk = blockIdx.x; chunk < 16384; chunk += 2048) {
    {
      float s1 = 0.f, sq = 0.f;
#pragma unroll
      for (int j = 0; j < 8; ++j) { s1 += pf[j]; sq += pf[j]*pf[j]; }
#pragma unroll
      for (int m = 1; m < 8; m <<= 1) {
        s1 += __shfl_xor(s1, m);
        sq += __shfl_xor(sq, m);
      }
      const float mu  = s1 * 0.015625f;
      const float var = sq * 0.015625f - mu * mu;
      const float rs  = rsqrtf(var + 1e-5f);
      short8 av;
#pragma unroll
      for (int j = 0; j < 8; ++j)
        av[j] = (short)f2bf((pf[j] - mu) * rs * g2v[j] + be2v[j]);
      *(short8*)&aL[ltok*72 + cg*8] = av;
      *(f32x4*)&yL[ltok*68 + cg*8]     = (f32x4){pf[0], pf[1], pf[2], pf[3]};
      *(f32x4*)&yL[ltok*68 + cg*8 + 4] = (f32x4){pf[4], pf[5], pf[6], pf[7]};
    }
    if (chunk + 2048 < 16384) {
      const float* p = &io[((chunk + 2048)*32 + ltok)*64 + cg*8];
      const f32x4 a = *(const f32x4*)p;
      const f32x4 c = *(const f32x4*)(p + 4);
      pf[0]=a[0]; pf[1]=a[1]; pf[2]=a[2]; pf[3]=a[3];
      pf[4]=c[0]; pf[5]=c[1]; pf[6]=c[2]; pf[7]=c[3];
    }
    __syncthreads();
    {
      short8 aF[2][2];
#pragma unroll
      for (int mt = 0; mt < 2; ++mt)
#pragma unroll
        for (int kt = 0; kt < 2; ++kt)
          aF[mt][kt] = *(const short8*)&aL[(mt*16 + col)*72 + kt*32 + quad*8];
#pragma unroll
      for (int nt = 0; nt < 4; ++nt) {
        f32x4 m0 = (f32x4){0.f,0.f,0.f,0.f}, m1 = (f32x4){0.f,0.f,0.f,0.f};
        m0 = MFMA(aF[0][0], b1f[0][nt], m0, 0, 0, 0);
        m0 = MFMA(aF[0][1], b1f[1][nt], m0, 0, 0, 0);
        m1 = MFMA(aF[1][0], b1f[0][nt], m1, 0, 0, 0);
        m1 = MFMA(aF[1][1], b1f[1][nt], m1, 0, 0, 0);
        const float bb = b1vv[nt];
#pragma unroll
        for (int r = 0; r < 4; ++r) {
          {
            const float h = m0[r] + bb;
            const float u = h * (1.5957691216f + 0.0713548162f * (h * h));
            const float e = __expf(u);
            hL[(quad*4 + r)*264 + w*64 + nt*16 + col] =
                f2bf(h - h * __builtin_amdgcn_rcpf(e + 1.f));
          }
          {
            const float h = m1[r] + bb;
            const float u = h * (1.5957691216f + 0.0713548162f * (h * h));
            const float e = __expf(u);
            hL[(16 + quad*4 + r)*264 + w*64 + nt*16 + col] =
                f2bf(h - h * __builtin_amdgcn_rcpf(e + 1.f));
          }
        }
      }
    }
    __syncthreads();
    {
      f32x4 o0 = (f32x4){0.f,0.f,0.f,0.f}, o1 = (f32x4){0.f,0.f,0.f,0.f};
#pragma unroll
      for (int kt = 0; kt < 8; ++kt) {
        o0 = MFMA(*(const short8*)&hL[(col)*264 + kt*32 + quad*8],    b2f[kt], o0, 0, 0, 0);
        o1 = MFMA(*(const short8*)&hL[(16+col)*264 + kt*32 + quad*8], b2f[kt], o1, 0, 0, 0);
      }
#pragma unroll
      for (int r = 0; r < 4; ++r) {
        const int r0 = quad*4 + r, r1 = 16 + quad*4 + r;
        io[(chunk*32 + r0)*64 + w*16 + col] = yL[r0*68 + w*16 + col] + o0[r] + b2vv;
        io[(chunk*32 + r1)*64 + w*16 + col] = yL[r1*68 + w*16 + col] + o1[r] + b2vv;
      }
    }
    __syncthreads();
  }
}

__global__ __launch_bounds__(256, 4)
void mlpA_kernel(float* __restrict__ io,
                 const void* __restrict__ n2g, const void* __restrict__ n2b,
                 const void* __restrict__ mw1, const void* __restrict__ mb1,
                 const void* __restrict__ mw2, const void* __restrict__ mb2,
                 const int* __restrict__ flag)
{
  __shared__ __align__(16) u16   aL[32 * 72];
  __shared__ __align__(16) u16   hL[32 * 264];
  __shared__ __align__(16) float yL[32 * 68];
  if (*flag)
    mlpA_body<true >(io, n2g, n2b, mw1, mb1, mw2, mb2, aL, hL, yL);
  else
    mlpA_body<false>(io, n2g, n2b, mw1, mb1, mw2, mb2, aL, hL, yL);
}

extern "C" void kernel_launch(void* const* d_in, const int* in_sizes, int n_in,
                              void* d_out, int out_size, void* d_ws, size_t ws_size,
                              hipStream_t stream) {
  const void* x     = d_in[0];
  const void* n1g   = d_in[1];
  const void* n1b   = d_in[2];
  const void* qkvw  = d_in[3];
  const void* qkvb  = d_in[4];
  const void* rpb   = d_in[5];
  const void* projw = d_in[6];
  const void* projb = d_in[7];
  const void* n2g   = d_in[8];
  const void* n2b   = d_in[9];
  const void* mw1   = d_in[10];
  const void* mb1   = d_in[11];
  const void* mw2   = d_in[12];
  const void* mb2   = d_in[13];
  float* out = (float*)d_out;
  int* flag  = (int*)d_ws;

  const size_t need = 256 + (size_t)524288 * 64 * 2;   // flag + attnout bf16

  detect_kernel<<<dim3(1), dim3(64), 0, stream>>>(x, flag);
  if (ws_size >= need) {
    u16* wsattn = (u16*)((char*)d_ws + 256);
    attnB_kernel<<<dim3(2048), dim3(256), 0, stream>>>(
        x, n1g, n1b, qkvw, qkvb, rpb, projw, projb, flag, wsattn);
    mlpB_kernel<<<dim3(2048), dim3(256), 0, stream>>>(
        x, wsattn, out, n2g, n2b, mw1, mb1, mw2, mb2, flag);
  } else {
    attnA_kernel<<<dim3(2048), dim3(256), 0, stream>>>(
        x, n1g, n1b, qkvw, qkvb, rpb, projw, projb, flag, out);
    mlpA_kernel<<<dim3(2048), dim3(256), 0, stream>>>(
        out, n2g, n2b, mw1, mb1, mw2, mb2, flag);
  }
}

// Round 10
// 459.122 us; speedup vs baseline: 1.1411x; 1.1411x over previous
//
#include <hip/hip_runtime.h>
#include <math.h>

typedef unsigned short u16;
typedef unsigned int u32;
typedef __attribute__((ext_vector_type(8))) short short8;   // 8 bf16 (4 VGPRs)
typedef __attribute__((ext_vector_type(4))) float f32x4;

__device__ __forceinline__ float bf2f(u16 u) {
  union { u32 i; float f; } v; v.i = ((u32)u) << 16; return v.f;
}
__device__ __forceinline__ u16 f2bf(float f) {
  union { float f; u32 i; } v; v.f = f;
  u32 i = v.i;
  i += 0x7fffu + ((i >> 16) & 1u);   // round-to-nearest-even
  return (u16)(i >> 16);
}

// dtype-polymorphic loads (F32: inputs are float32; else bf16 bits)
template<bool F32>
__device__ __forceinline__ float ld(const void* p, int i) {
  if (F32) return ((const float*)p)[i];
  return bf2f(((const u16*)p)[i]);
}

// ---------------------------------------------------------------------------
// Kernel 0: detect input dtype (fp32 vs bf16-packed).
// ---------------------------------------------------------------------------
__global__ __launch_bounds__(64)
void detect_kernel(const void* __restrict__ xv, int* __restrict__ flag) {
  const u32* xw = (const u32*)xv;
  const int t = threadIdx.x;
  int bad = 0;
  for (int i = t; i < 1024; i += 64) {
    const int e = (int)((xw[i] >> 7) & 0xFF);
    if (e < 90 || e > 150) bad++;
  }
#pragma unroll
  for (int m = 1; m < 64; m <<= 1) bad += __shfl_xor(bad, m);
  if (t == 0) *flag = (bad > 256) ? 1 : 0;
}

// ---------------------------------------------------------------------------
// Token-major shifted gather: lane (s, cg) loads token s's channels cg*8..+7
// of window (wbase + w) as two 16B loads (8 lanes cover a 256B row).
// ---------------------------------------------------------------------------
template<bool F32>
__device__ __forceinline__ void gather8(const void* __restrict__ x, int chunk,
                                        int w, int s, int cg, float* pf) {
  const int b     = chunk >> 13;
  const int wbase = (chunk & 8191) << 2;
  const int widx  = wbase + w;
  const int wz = widx >> 10, wy = (widx >> 5) & 31, wx = widx & 31;
  const int od = (2*wz + ((s>>2)&1) + 1) & 63;
  const int oh = (2*wy + ((s>>1)&1) + 1) & 63;
  const int ow = (2*wx + ( s    &1) + 1) & 63;
  const int base = (((b<<18) + ((od<<12)|(oh<<6)|ow)) << 6) + cg*8;
  if (F32) {
    const f32x4 a = *(const f32x4*)((const float*)x + base);
    const f32x4 c = *(const f32x4*)((const float*)x + base + 4);
    pf[0]=a[0]; pf[1]=a[1]; pf[2]=a[2]; pf[3]=a[3];
    pf[4]=c[0]; pf[5]=c[1]; pf[6]=c[2]; pf[7]=c[3];
  } else {
    const short8 a = *(const short8*)((const u16*)x + base);
#pragma unroll
    for (int j = 0; j < 8; ++j) pf[j] = bf2f((u16)a[j]);
  }
}

// bug-faithful window-reverse scatter base for token tok of chunk's windows
__device__ __forceinline__ int scat(int chunk, int tok) {
  const int b     = chunk >> 13;
  const int wbase = (chunk & 8191) << 2;
  const int widx = wbase + (tok >> 3);
  const int s    = tok & 7;
  const int wz = widx >> 10, wy = (widx >> 5) & 31, wx = widx & 31;
  const int fd = (2*wz + ((wy>>3)&1) + 1) & 63;
  const int Hb = 8*(wy&7) + 4*(wx>>4) + (wy>>4);
  const int Wb = 4*(wx&15);
  const int i = (s>>2)&1, j = (s>>1)&1, k = s&1;
  const int fh = (Hb + 2*j + 1) & 63;
  const int fw = (Wb + 2*i + k + 1) & 63;
  return ((b<<18) + ((fd<<12)|(fh<<6)|fw)) << 6;
}

#define MFMA __builtin_amdgcn_mfma_f32_16x16x32_bf16

// ---------------------------------------------------------------------------
// Kernel 1: LN1 + shifted-window attention + proj + residual -> out (y, fp32).
// EXACT round-4 verified version (148 us): persistent grid 2048, chunk = 4
// windows = 32 tokens, bf16 q/k/v LDS, register-resident fragments (fit in
// the compiler's 64-VGPR target, so no per-chunk spill reload).
// ---------------------------------------------------------------------------
template<bool F32>
__device__ __forceinline__ void attn_body(
    const void* __restrict__ x,
    const void* __restrict__ n1g, const void* __restrict__ n1b,
    const void* __restrict__ qkvw, const void* __restrict__ qkvb,
    const void* __restrict__ rpb,
    const void* __restrict__ projw, const void* __restrict__ projb,
    float* __restrict__ out,
    u16* __restrict__ aL, u16* __restrict__ qL,
    u16* __restrict__ kL, u16* __restrict__ vL)
{
  const int tid  = threadIdx.x;
  const int w    = tid >> 6, l = tid & 63;
  const int quad = l >> 4,  col = l & 15;
  const int s8   = l >> 3,  cg  = l & 7;   // token-major split (= head, query)

  float g1v[8], be1v[8];
#pragma unroll
  for (int j = 0; j < 8; ++j) {
    g1v[j]  = ld<F32>(n1g, cg*8 + j);
    be1v[j] = ld<F32>(n1b, cg*8 + j);
  }

  short8 bq[3][2];                 // qkv cols w*48 + nt*16 + col, [nt][kt]
#pragma unroll
  for (int nt = 0; nt < 3; ++nt)
#pragma unroll
    for (int kt = 0; kt < 2; ++kt) {
      short8 f;
#pragma unroll
      for (int j = 0; j < 8; ++j)
        f[j] = (short)f2bf(ld<F32>(qkvw, (kt*32 + quad*8 + j)*192 + w*48 + nt*16 + col));
      bq[nt][kt] = f;
    }
  float qb[3];
#pragma unroll
  for (int nt = 0; nt < 3; ++nt) qb[nt] = ld<F32>(qkvb, w*48 + nt*16 + col);
  short8 bp[2];                    // proj cols w*16 + col, [kt]
#pragma unroll
  for (int kt = 0; kt < 2; ++kt) {
    short8 f;
#pragma unroll
    for (int j = 0; j < 8; ++j)
      f[j] = (short)f2bf(ld<F32>(projw, (kt*32 + quad*8 + j)*64 + w*16 + col));
    bp[kt] = f;
  }
  const float pbv = ld<F32>(projb, w*16 + col);
  const int rel = 3 * (((s8>>1)&1) - ((cg>>1)&1) + 1)
                +     (((s8>>2)&1) - ((cg>>2)&1) + 1)
                +     (( s8    &1) - ( cg    &1) + 1);
  float rpv[8];
#pragma unroll
  for (int kk = 0; kk < 8; ++kk) rpv[kk] = ld<F32>(rpb, rel*8 + kk);

  float pf[8];
  gather8<F32>(x, blockIdx.x, w, s8, cg, pf);   // prologue prefetch

  for (int chunk = blockIdx.x; chunk < 16384; chunk += 2048) {
    const int wbase = (chunk & 8191) << 2;
    const int widx0 = wbase + w;
    const int wz0 = widx0 >> 10, wy0 = (widx0 >> 5) & 31, wx0 = widx0 & 31;

    // ---- phase 1: LN1, token-major 3-stage group reduce ----
    {
      float s1 = 0.f, sq = 0.f;
#pragma unroll
      for (int j = 0; j < 8; ++j) { s1 += pf[j]; sq += pf[j]*pf[j]; }
#pragma unroll
      for (int m = 1; m < 8; m <<= 1) {
        s1 += __shfl_xor(s1, m);
        sq += __shfl_xor(sq, m);
      }
      const float mu  = s1 * 0.015625f;
      const float var = sq * 0.015625f - mu * mu;
      const float rs  = rsqrtf(var + 1e-5f);
      short8 av;
#pragma unroll
      for (int j = 0; j < 8; ++j)
        av[j] = (short)f2bf((pf[j] - mu) * rs * g1v[j] + be1v[j]);
      *(short8*)&aL[(w*8 + s8)*72 + cg*8] = av;
    }
    if (chunk + 2048 < 16384) gather8<F32>(x, chunk + 2048, w, s8, cg, pf);
    __syncthreads();                                       // B1: aL ready

    // ---- phase 2: QKV MFMA, A[32x64] @ wave's 64x48 slab -> q/k/v LDS ----
    {
      short8 aF[2][2];
#pragma unroll
      for (int mt = 0; mt < 2; ++mt)
#pragma unroll
        for (int kt = 0; kt < 2; ++kt)
          aF[mt][kt] = *(const short8*)&aL[(mt*16 + col)*72 + kt*32 + quad*8];
#pragma unroll
      for (int nt = 0; nt < 3; ++nt) {
        f32x4 a0 = (f32x4){0.f,0.f,0.f,0.f}, a1 = (f32x4){0.f,0.f,0.f,0.f};
        a0 = MFMA(aF[0][0], bq[nt][0], a0, 0, 0, 0);
        a0 = MFMA(aF[0][1], bq[nt][1], a0, 0, 0, 0);
        a1 = MFMA(aF[1][0], bq[nt][0], a1, 0, 0, 0);
        a1 = MFMA(aF[1][1], bq[nt][1], a1, 0, 0, 0);
        const int nb  = w*48 + nt*16;
        u16* dst      = (nb < 64) ? qL : (nb < 128) ? kL : vL;
        const int chb = (nb & 63) + col;
        const float scl = (nb < 64) ? 0.35355339059327373f : 1.0f;
        const float bb  = qb[nt];
#pragma unroll
        for (int r = 0; r < 4; ++r) {
          dst[(quad*4 + r)*72 + chb]      = f2bf((a0[r] + bb) * scl);
          dst[(16 + quad*4 + r)*72 + chb] = f2bf((a1[r] + bb) * scl);
        }
      }
    }
    __syncthreads();                                       // B2: q/k/v ready

    // ---- phase 3: softmax for window w (lane = (head s8, query cg)) ----
    {
      const int tq = w*8 + cg;
      float qr[8];
      {
        const short8 qv = *(const short8*)&qL[tq*72 + s8*8];
#pragma unroll
        for (int d = 0; d < 8; ++d) qr[d] = bf2f((u16)qv[d]);
      }
      float sc8[8];
#pragma unroll
      for (int kk = 0; kk < 8; ++kk) {
        const short8 kv = *(const short8*)&kL[(w*8 + kk)*72 + s8*8];
        float a = 0.f;
#pragma unroll
        for (int d = 0; d < 8; ++d) a += qr[d] * bf2f((u16)kv[d]);
        sc8[kk] = a + rpv[kk];
      }
      {
        int cnts[8];
#pragma unroll
        for (int p = 0; p < 8; ++p) {
          const int sd = 2*wz0 + ((p>>2)&1);
          const int sh = 2*wy0 + ((p>>1)&1);
          const int sw = 2*wx0 + (p&1);
          cnts[p] = (sd >= 62 ? sd - 61 : 0)*9 + (sh >= 62 ? sh - 61 : 0)*3
                  + (sw >= 62 ? sw - 61 : 0);
        }
#pragma unroll
        for (int kk = 0; kk < 8; ++kk)
          if (cnts[kk] != cnts[cg]) sc8[kk] -= 100.f;
      }
      float mx = sc8[0];
#pragma unroll
      for (int kk = 1; kk < 8; ++kk) mx = fmaxf(mx, sc8[kk]);
      float pr[8], lsum = 0.f;
#pragma unroll
      for (int kk = 0; kk < 8; ++kk) { pr[kk] = __expf(sc8[kk] - mx); lsum += pr[kk]; }
      const float inv = __builtin_amdgcn_rcpf(lsum);
      float o[8];
#pragma unroll
      for (int d = 0; d < 8; ++d) o[d] = 0.f;
#pragma unroll
      for (int kk = 0; kk < 8; ++kk) {
        const short8 vv = *(const short8*)&vL[(w*8 + kk)*72 + s8*8];
#pragma unroll
        for (int d = 0; d < 8; ++d) o[d] += pr[kk] * bf2f((u16)vv[d]);
      }
      short8 ov;
#pragma unroll
      for (int d = 0; d < 8; ++d) ov[d] = (short)f2bf(o[d] * inv);
      *(short8*)&qL[tq*72 + s8*8] = ov;    // O into own q-slot
    }
    // prefetch residual x + scatter offsets (x is L3-resident)
    int offs[8]; float xr[8];
#pragma unroll
    for (int mt = 0; mt < 2; ++mt)
#pragma unroll
      for (int r = 0; r < 4; ++r) {
        const int off = scat(chunk, mt*16 + quad*4 + r) + w*16 + col;
        offs[mt*4 + r] = off;
        xr[mt*4 + r]   = ld<F32>(x, off);
      }
    __syncthreads();                                       // B3: O ready

    // ---- phase 4: proj MFMA (A = O from qL) + scattered residual write ----
    {
      f32x4 c0 = (f32x4){0.f,0.f,0.f,0.f}, c1 = (f32x4){0.f,0.f,0.f,0.f};
      c0 = MFMA(*(const short8*)&qL[(col)*72 + quad*8],         bp[0], c0, 0, 0, 0);
      c0 = MFMA(*(const short8*)&qL[(col)*72 + 32 + quad*8],    bp[1], c0, 0, 0, 0);
      c1 = MFMA(*(const short8*)&qL[(16+col)*72 + quad*8],      bp[0], c1, 0, 0, 0);
      c1 = MFMA(*(const short8*)&qL[(16+col)*72 + 32 + quad*8], bp[1], c1, 0, 0, 0);
#pragma unroll
      for (int r = 0; r < 4; ++r) {
        out[offs[r]]     = xr[r]     + c0[r] + pbv;
        out[offs[4 + r]] = xr[4 + r] + c1[r] + pbv;
      }
    }
    __syncthreads();   // B4: fence qL reads vs next chunk's phase-2 writes
  }
}

__global__ __launch_bounds__(256, 4)
void attn_kernel(const void* __restrict__ x,
                 const void* __restrict__ n1g, const void* __restrict__ n1b,
                 const void* __restrict__ qkvw, const void* __restrict__ qkvb,
                 const void* __restrict__ rpb,
                 const void* __restrict__ projw, const void* __restrict__ projb,
                 const int* __restrict__ flag, float* __restrict__ out)
{
  __shared__ __align__(16) u16 aL[32*72];   // 4.6 KB
  __shared__ __align__(16) u16 qL[32*72];   // 4.6 KB (q, then O)
  __shared__ __align__(16) u16 kL[32*72];   // 4.6 KB
  __shared__ __align__(16) u16 vL[32*72];   // 4.6 KB  (18.4 KB total)
  if (*flag)
    attn_body<true >(x, n1g, n1b, qkvw, qkvb, rpb, projw, projb, out, aL, qL, kL, vL);
  else
    attn_body<false>(x, n1g, n1b, qkvw, qkvb, rpb, projw, projb, out, aL, qL, kL, vL);
}

// ---------------------------------------------------------------------------
// Kernel 2: LN2 + MLP(64->256 GELU ->64) + residual, in-place on out (=y).
// NON-PERSISTENT: grid 16384, one 32-token chunk per block. Weight fragments
// are loaded once per block with short live ranges -- no per-chunk spill
// reloads (the r4..r9 persistent variants spilled ~50 VGPRs of fragments to
// scratch and re-read them every chunk through a thrashed L2 -> extra HBM
// traffic). Weights stay L2/L3-hot across blocks (~130 KB shared set).
// ---------------------------------------------------------------------------
template<bool F32>
__device__ __forceinline__ void mlp_body(
    float* __restrict__ io,
    const void* __restrict__ n2g, const void* __restrict__ n2b,
    const void* __restrict__ mw1, const void* __restrict__ mb1,
    const void* __restrict__ mw2, const void* __restrict__ mb2,
    u16* __restrict__ aL, u16* __restrict__ hL, float* __restrict__ yL)
{
  const int tid  = threadIdx.x;
  const int w    = tid >> 6, l = tid & 63;
  const int quad = l >> 4,  col = l & 15;
  const int s8   = l >> 3,  cg  = l & 7;
  const int ltok = w*8 + s8;
  const int chunk = blockIdx.x;

  // ---- issue the io read immediately (hides under weight loads) ----
  float pf[8];
  {
    const float* p = &io[(chunk*32 + ltok)*64 + cg*8];
    const f32x4 a = *(const f32x4*)p;
    const f32x4 c = *(const f32x4*)(p + 4);
    pf[0]=a[0]; pf[1]=a[1]; pf[2]=a[2]; pf[3]=a[3];
    pf[4]=c[0]; pf[5]=c[1]; pf[6]=c[2]; pf[7]=c[3];
  }

  float g2v[8], be2v[8];
#pragma unroll
  for (int j = 0; j < 8; ++j) {
    g2v[j]  = ld<F32>(n2g, cg*8 + j);
    be2v[j] = ld<F32>(n2b, cg*8 + j);
  }
  float b1vv[4];
#pragma unroll
  for (int nt = 0; nt < 4; ++nt) b1vv[nt] = ld<F32>(mb1, w*64 + nt*16 + col);
  const float b2vv = ld<F32>(mb2, w*16 + col);

  // W1 fragments (used in phase 1 only)
  short8 b1f[2][4];                  // [kt][nt], W1 cols w*64+nt*16+col
#pragma unroll
  for (int kt = 0; kt < 2; ++kt)
#pragma unroll
    for (int nt = 0; nt < 4; ++nt) {
      short8 f;
#pragma unroll
      for (int j = 0; j < 8; ++j)
        f[j] = (short)f2bf(ld<F32>(mw1, (kt*32 + quad*8 + j)*256 + w*64 + nt*16 + col));
      b1f[kt][nt] = f;
    }

  // ---- LN2 (token-major group reduce) + stash y in yL ----
  {
    float s1 = 0.f, sq = 0.f;
#pragma unroll
    for (int j = 0; j < 8; ++j) { s1 += pf[j]; sq += pf[j]*pf[j]; }
#pragma unroll
    for (int m = 1; m < 8; m <<= 1) {
      s1 += __shfl_xor(s1, m);
      sq += __shfl_xor(sq, m);
    }
    const float mu  = s1 * 0.015625f;
    const float var = sq * 0.015625f - mu * mu;
    const float rs  = rsqrtf(var + 1e-5f);
    short8 av;
#pragma unroll
    for (int j = 0; j < 8; ++j)
      av[j] = (short)f2bf((pf[j] - mu) * rs * g2v[j] + be2v[j]);
    *(short8*)&aL[ltok*72 + cg*8] = av;
    *(f32x4*)&yL[ltok*68 + cg*8]     = (f32x4){pf[0], pf[1], pf[2], pf[3]};
    *(f32x4*)&yL[ltok*68 + cg*8 + 4] = (f32x4){pf[4], pf[5], pf[6], pf[7]};
  }
  __syncthreads();                                       // B1: aL/yL ready

  // ---- phase 1: 32x64 @ 64x256 -> wave's 32x64 slab, GELU -> hL ----
  {
    short8 aF[2][2];
#pragma unroll
    for (int mt = 0; mt < 2; ++mt)
#pragma unroll
      for (int kt = 0; kt < 2; ++kt)
        aF[mt][kt] = *(const short8*)&aL[(mt*16 + col)*72 + kt*32 + quad*8];
#pragma unroll
    for (int nt = 0; nt < 4; ++nt) {
      f32x4 m0 = (f32x4){0.f,0.f,0.f,0.f}, m1 = (f32x4){0.f,0.f,0.f,0.f};
      m0 = MFMA(aF[0][0], b1f[0][nt], m0, 0, 0, 0);
      m0 = MFMA(aF[0][1], b1f[1][nt], m0, 0, 0, 0);
      m1 = MFMA(aF[1][0], b1f[0][nt], m1, 0, 0, 0);
      m1 = MFMA(aF[1][1], b1f[1][nt], m1, 0, 0, 0);
      const float bb = b1vv[nt];
#pragma unroll
      for (int r = 0; r < 4; ++r) {
        {
          const float h = m0[r] + bb;
          const float u = h * (1.5957691216f + 0.0713548162f * (h * h));
          const float e = __expf(u);
          hL[(quad*4 + r)*264 + w*64 + nt*16 + col] =
              f2bf(h - h * __builtin_amdgcn_rcpf(e + 1.f));
        }
        {
          const float h = m1[r] + bb;
          const float u = h * (1.5957691216f + 0.0713548162f * (h * h));
          const float e = __expf(u);
          hL[(16 + quad*4 + r)*264 + w*64 + nt*16 + col] =
              f2bf(h - h * __builtin_amdgcn_rcpf(e + 1.f));
        }
      }
    }
  }

  // W2 fragments (loaded after W1 is dead; used in phase 2 only)
  short8 b2f[8];                     // [kt], W2 col w*16+col
#pragma unroll
  for (int kt = 0; kt < 8; ++kt) {
    short8 f;
#pragma unroll
    for (int j = 0; j < 8; ++j)
      f[j] = (short)f2bf(ld<F32>(mw2, (kt*32 + quad*8 + j)*64 + w*16 + col));
    b2f[kt] = f;
  }
  __syncthreads();                                       // B2: hL ready

  // ---- phase 2: 32x256 @ 256x64 + residual from yL -> out ----
  {
    f32x4 o0 = (f32x4){0.f,0.f,0.f,0.f}, o1 = (f32x4){0.f,0.f,0.f,0.f};
#pragma unroll
    for (int kt = 0; kt < 8; ++kt) {
      o0 = MFMA(*(const short8*)&hL[(col)*264 + kt*32 + quad*8],    b2f[kt], o0, 0, 0, 0);
      o1 = MFMA(*(const short8*)&hL[(16+col)*264 + kt*32 + quad*8], b2f[kt], o1, 0, 0, 0);
    }
#pragma unroll
    for (int r = 0; r < 4; ++r) {
      const int r0 = quad*4 + r, r1 = 16 + quad*4 + r;
      io[(chunk*32 + r0)*64 + w*16 + col] = yL[r0*68 + w*16 + col] + o0[r] + b2vv;
      io[(chunk*32 + r1)*64 + w*16 + col] = yL[r1*68 + w*16 + col] + o1[r] + b2vv;
    }
  }
}

__global__ __launch_bounds__(256, 4)
void mlp_kernel(float* __restrict__ io,
                const void* __restrict__ n2g, const void* __restrict__ n2b,
                const void* __restrict__ mw1, const void* __restrict__ mb1,
                const void* __restrict__ mw2, const void* __restrict__ mb2,
                const int* __restrict__ flag)
{
  __shared__ __align__(16) u16   aL[32 * 72];    //  4.6 KB
  __shared__ __align__(16) u16   hL[32 * 264];   // 16.9 KB
  __shared__ __align__(16) float yL[32 * 68];    //  8.7 KB  (30.2 KB total)
  if (*flag)
    mlp_body<true >(io, n2g, n2b, mw1, mb1, mw2, mb2, aL, hL, yL);
  else
    mlp_body<false>(io, n2g, n2b, mw1, mb1, mw2, mb2, aL, hL, yL);
}

extern "C" void kernel_launch(void* const* d_in, const int* in_sizes, int n_in,
                              void* d_out, int out_size, void* d_ws, size_t ws_size,
                              hipStream_t stream) {
  const void* x     = d_in[0];
  const void* n1g   = d_in[1];
  const void* n1b   = d_in[2];
  const void* qkvw  = d_in[3];
  const void* qkvb  = d_in[4];
  const void* rpb   = d_in[5];
  const void* projw = d_in[6];
  const void* projb = d_in[7];
  const void* n2g   = d_in[8];
  const void* n2b   = d_in[9];
  const void* mw1   = d_in[10];
  const void* mb1   = d_in[11];
  const void* mw2   = d_in[12];
  const void* mb2   = d_in[13];
  float* out = (float*)d_out;
  int* flag  = (int*)d_ws;

  detect_kernel<<<dim3(1), dim3(64), 0, stream>>>(x, flag);
  attn_kernel<<<dim3(2048), dim3(256), 0, stream>>>(
      x, n1g, n1b, qkvw, qkvb, rpb, projw, projb, flag, out);
  mlp_kernel<<<dim3(16384), dim3(256), 0, stream>>>(
      out, n2g, n2b, mw1, mb1, mw2, mb2, flag);
}

// Round 11
// 414.466 us; speedup vs baseline: 1.2640x; 1.1077x over previous
//
#include <hip/hip_runtime.h>
#include <math.h>

typedef unsigned short u16;
typedef unsigned int u32;
typedef __attribute__((ext_vector_type(8))) short short8;   // 8 bf16 (4 VGPRs)
typedef __attribute__((ext_vector_type(4))) float f32x4;

__device__ __forceinline__ float bf2f(u16 u) {
  union { u32 i; float f; } v; v.i = ((u32)u) << 16; return v.f;
}
__device__ __forceinline__ u16 f2bf(float f) {
  union { float f; u32 i; } v; v.f = f;
  u32 i = v.i;
  i += 0x7fffu + ((i >> 16) & 1u);   // round-to-nearest-even
  return (u16)(i >> 16);
}

// dtype-polymorphic loads (F32: inputs are float32; else bf16 bits)
template<bool F32>
__device__ __forceinline__ float ld(const void* p, int i) {
  if (F32) return ((const float*)p)[i];
  return bf2f(((const u16*)p)[i]);
}

// ---------------------------------------------------------------------------
// Kernel 0: detect input dtype (fp32 vs bf16-packed).
// ---------------------------------------------------------------------------
__global__ __launch_bounds__(64)
void detect_kernel(const void* __restrict__ xv, int* __restrict__ flag) {
  const u32* xw = (const u32*)xv;
  const int t = threadIdx.x;
  int bad = 0;
  for (int i = t; i < 1024; i += 64) {
    const int e = (int)((xw[i] >> 7) & 0xFF);
    if (e < 90 || e > 150) bad++;
  }
#pragma unroll
  for (int m = 1; m < 64; m <<= 1) bad += __shfl_xor(bad, m);
  if (t == 0) *flag = (bad > 256) ? 1 : 0;
}

// ---------------------------------------------------------------------------
// Kernel 0.5: pack MLP weight fragments (bf16, MFMA B-layout) into ws.
// Layouts match mlp_body's per-thread access exactly:
//   wsb1[(((w*2+kt)*4+nt)*64 + l)*8 + j] = bf16(mw1[(kt*32+quad*8+j)*256 + w*64+nt*16+col])
//   wsb2[(((w*8+kt)   )*64 + l)*8 + j]  = bf16(mw2[(kt*32+quad*8+j)*64  + w*16+col])
// ---------------------------------------------------------------------------
template<bool F32>
__device__ __forceinline__ void pack_body(const void* __restrict__ mw1,
                                          const void* __restrict__ mw2,
                                          u16* __restrict__ wsb1,
                                          u16* __restrict__ wsb2) {
  const int g  = blockIdx.x * 256 + threadIdx.x;
  const int gs = gridDim.x * 256;
  for (int e = g; e < 16384; e += gs) {
    const int j = e & 7, l = (e >> 3) & 63, nt = (e >> 9) & 3,
              kt = (e >> 11) & 1, w = e >> 12;
    const int quad = l >> 4, col = l & 15;
    wsb1[e] = f2bf(ld<F32>(mw1, (kt*32 + quad*8 + j)*256 + w*64 + nt*16 + col));
  }
  for (int e = g; e < 16384; e += gs) {
    const int j = e & 7, l = (e >> 3) & 63, kt = (e >> 9) & 7, w = e >> 12;
    const int quad = l >> 4, col = l & 15;
    wsb2[e] = f2bf(ld<F32>(mw2, (kt*32 + quad*8 + j)*64 + w*16 + col));
  }
}

__global__ __launch_bounds__(256)
void pack_kernel(const void* __restrict__ mw1, const void* __restrict__ mw2,
                 u16* __restrict__ wsb1, u16* __restrict__ wsb2,
                 const int* __restrict__ flag) {
  if (*flag) pack_body<true >(mw1, mw2, wsb1, wsb2);
  else       pack_body<false>(mw1, mw2, wsb1, wsb2);
}

// ---------------------------------------------------------------------------
// Token-major shifted gather: lane (s, cg) loads token s's channels cg*8..+7
// of window (wbase + w) as two 16B loads (8 lanes cover a 256B row).
// ---------------------------------------------------------------------------
template<bool F32>
__device__ __forceinline__ void gather8(const void* __restrict__ x, int chunk,
                                        int w, int s, int cg, float* pf) {
  const int b     = chunk >> 13;
  const int wbase = (chunk & 8191) << 2;
  const int widx  = wbase + w;
  const int wz = widx >> 10, wy = (widx >> 5) & 31, wx = widx & 31;
  const int od = (2*wz + ((s>>2)&1) + 1) & 63;
  const int oh = (2*wy + ((s>>1)&1) + 1) & 63;
  const int ow = (2*wx + ( s    &1) + 1) & 63;
  const int base = (((b<<18) + ((od<<12)|(oh<<6)|ow)) << 6) + cg*8;
  if (F32) {
    const f32x4 a = *(const f32x4*)((const float*)x + base);
    const f32x4 c = *(const f32x4*)((const float*)x + base + 4);
    pf[0]=a[0]; pf[1]=a[1]; pf[2]=a[2]; pf[3]=a[3];
    pf[4]=c[0]; pf[5]=c[1]; pf[6]=c[2]; pf[7]=c[3];
  } else {
    const short8 a = *(const short8*)((const u16*)x + base);
#pragma unroll
    for (int j = 0; j < 8; ++j) pf[j] = bf2f((u16)a[j]);
  }
}

// bug-faithful window-reverse scatter base for token tok of chunk's windows
__device__ __forceinline__ int scat(int chunk, int tok) {
  const int b     = chunk >> 13;
  const int wbase = (chunk & 8191) << 2;
  const int widx = wbase + (tok >> 3);
  const int s    = tok & 7;
  const int wz = widx >> 10, wy = (widx >> 5) & 31, wx = widx & 31;
  const int fd = (2*wz + ((wy>>3)&1) + 1) & 63;
  const int Hb = 8*(wy&7) + 4*(wx>>4) + (wy>>4);
  const int Wb = 4*(wx&15);
  const int i = (s>>2)&1, j = (s>>1)&1, k = s&1;
  const int fh = (Hb + 2*j + 1) & 63;
  const int fw = (Wb + 2*i + k + 1) & 63;
  return ((b<<18) + ((fd<<12)|(fh<<6)|fw)) << 6;
}

#define MFMA __builtin_amdgcn_mfma_f32_16x16x32_bf16

// ---------------------------------------------------------------------------
// Kernel 1: LN1 + shifted-window attention + proj -> out[scat] = attn + pb.
// NO residual here (moved to mlp: residual is elementwise in output index
// space, so mlp can read x linearly). r4 structure otherwise; B4 dropped
// (B1 of the next chunk already fences phase-4 qL reads vs phase-2 writes).
// ---------------------------------------------------------------------------
template<bool F32>
__device__ __forceinline__ void attn_body(
    const void* __restrict__ x,
    const void* __restrict__ n1g, const void* __restrict__ n1b,
    const void* __restrict__ qkvw, const void* __restrict__ qkvb,
    const void* __restrict__ rpb,
    const void* __restrict__ projw, const void* __restrict__ projb,
    float* __restrict__ out,
    u16* __restrict__ aL, u16* __restrict__ qL,
    u16* __restrict__ kL, u16* __restrict__ vL)
{
  const int tid  = threadIdx.x;
  const int w    = tid >> 6, l = tid & 63;
  const int quad = l >> 4,  col = l & 15;
  const int s8   = l >> 3,  cg  = l & 7;   // token-major split (= head, query)

  float g1v[8], be1v[8];
#pragma unroll
  for (int j = 0; j < 8; ++j) {
    g1v[j]  = ld<F32>(n1g, cg*8 + j);
    be1v[j] = ld<F32>(n1b, cg*8 + j);
  }

  short8 bq[3][2];                 // qkv cols w*48 + nt*16 + col, [nt][kt]
#pragma unroll
  for (int nt = 0; nt < 3; ++nt)
#pragma unroll
    for (int kt = 0; kt < 2; ++kt) {
      short8 f;
#pragma unroll
      for (int j = 0; j < 8; ++j)
        f[j] = (short)f2bf(ld<F32>(qkvw, (kt*32 + quad*8 + j)*192 + w*48 + nt*16 + col));
      bq[nt][kt] = f;
    }
  float qb[3];
#pragma unroll
  for (int nt = 0; nt < 3; ++nt) qb[nt] = ld<F32>(qkvb, w*48 + nt*16 + col);
  short8 bp[2];                    // proj cols w*16 + col, [kt]
#pragma unroll
  for (int kt = 0; kt < 2; ++kt) {
    short8 f;
#pragma unroll
    for (int j = 0; j < 8; ++j)
      f[j] = (short)f2bf(ld<F32>(projw, (kt*32 + quad*8 + j)*64 + w*16 + col));
    bp[kt] = f;
  }
  const float pbv = ld<F32>(projb, w*16 + col);
  const int rel = 3 * (((s8>>1)&1) - ((cg>>1)&1) + 1)
                +     (((s8>>2)&1) - ((cg>>2)&1) + 1)
                +     (( s8    &1) - ( cg    &1) + 1);
  float rpv[8];
#pragma unroll
  for (int kk = 0; kk < 8; ++kk) rpv[kk] = ld<F32>(rpb, rel*8 + kk);

  float pf[8];
  gather8<F32>(x, blockIdx.x, w, s8, cg, pf);   // prologue prefetch

  for (int chunk = blockIdx.x; chunk < 16384; chunk += 2048) {
    const int wbase = (chunk & 8191) << 2;
    const int widx0 = wbase + w;
    const int wz0 = widx0 >> 10, wy0 = (widx0 >> 5) & 31, wx0 = widx0 & 31;

    // ---- phase 1: LN1, token-major 3-stage group reduce ----
    {
      float s1 = 0.f, sq = 0.f;
#pragma unroll
      for (int j = 0; j < 8; ++j) { s1 += pf[j]; sq += pf[j]*pf[j]; }
#pragma unroll
      for (int m = 1; m < 8; m <<= 1) {
        s1 += __shfl_xor(s1, m);
        sq += __shfl_xor(sq, m);
      }
      const float mu  = s1 * 0.015625f;
      const float var = sq * 0.015625f - mu * mu;
      const float rs  = rsqrtf(var + 1e-5f);
      short8 av;
#pragma unroll
      for (int j = 0; j < 8; ++j)
        av[j] = (short)f2bf((pf[j] - mu) * rs * g1v[j] + be1v[j]);
      *(short8*)&aL[(w*8 + s8)*72 + cg*8] = av;
    }
    if (chunk + 2048 < 16384) gather8<F32>(x, chunk + 2048, w, s8, cg, pf);
    __syncthreads();                                       // B1: aL ready

    // ---- phase 2: QKV MFMA, A[32x64] @ wave's 64x48 slab -> q/k/v LDS ----
    {
      short8 aF[2][2];
#pragma unroll
      for (int mt = 0; mt < 2; ++mt)
#pragma unroll
        for (int kt = 0; kt < 2; ++kt)
          aF[mt][kt] = *(const short8*)&aL[(mt*16 + col)*72 + kt*32 + quad*8];
#pragma unroll
      for (int nt = 0; nt < 3; ++nt) {
        f32x4 a0 = (f32x4){0.f,0.f,0.f,0.f}, a1 = (f32x4){0.f,0.f,0.f,0.f};
        a0 = MFMA(aF[0][0], bq[nt][0], a0, 0, 0, 0);
        a0 = MFMA(aF[0][1], bq[nt][1], a0, 0, 0, 0);
        a1 = MFMA(aF[1][0], bq[nt][0], a1, 0, 0, 0);
        a1 = MFMA(aF[1][1], bq[nt][1], a1, 0, 0, 0);
        const int nb  = w*48 + nt*16;
        u16* dst      = (nb < 64) ? qL : (nb < 128) ? kL : vL;
        const int chb = (nb & 63) + col;
        const float scl = (nb < 64) ? 0.35355339059327373f : 1.0f;
        const float bb  = qb[nt];
#pragma unroll
        for (int r = 0; r < 4; ++r) {
          dst[(quad*4 + r)*72 + chb]      = f2bf((a0[r] + bb) * scl);
          dst[(16 + quad*4 + r)*72 + chb] = f2bf((a1[r] + bb) * scl);
        }
      }
    }
    __syncthreads();                                       // B2: q/k/v ready

    // ---- phase 3: softmax for window w (lane = (head s8, query cg)) ----
    {
      const int tq = w*8 + cg;
      float qr[8];
      {
        const short8 qv = *(const short8*)&qL[tq*72 + s8*8];
#pragma unroll
        for (int d = 0; d < 8; ++d) qr[d] = bf2f((u16)qv[d]);
      }
      float sc8[8];
#pragma unroll
      for (int kk = 0; kk < 8; ++kk) {
        const short8 kv = *(const short8*)&kL[(w*8 + kk)*72 + s8*8];
        float a = 0.f;
#pragma unroll
        for (int d = 0; d < 8; ++d) a += qr[d] * bf2f((u16)kv[d]);
        sc8[kk] = a + rpv[kk];
      }
      {
        int cnts[8];
#pragma unroll
        for (int p = 0; p < 8; ++p) {
          const int sd = 2*wz0 + ((p>>2)&1);
          const int sh = 2*wy0 + ((p>>1)&1);
          const int sw = 2*wx0 + (p&1);
          cnts[p] = (sd >= 62 ? sd - 61 : 0)*9 + (sh >= 62 ? sh - 61 : 0)*3
                  + (sw >= 62 ? sw - 61 : 0);
        }
#pragma unroll
        for (int kk = 0; kk < 8; ++kk)
          if (cnts[kk] != cnts[cg]) sc8[kk] -= 100.f;
      }
      float mx = sc8[0];
#pragma unroll
      for (int kk = 1; kk < 8; ++kk) mx = fmaxf(mx, sc8[kk]);
      float pr[8], lsum = 0.f;
#pragma unroll
      for (int kk = 0; kk < 8; ++kk) { pr[kk] = __expf(sc8[kk] - mx); lsum += pr[kk]; }
      const float inv = __builtin_amdgcn_rcpf(lsum);
      float o[8];
#pragma unroll
      for (int d = 0; d < 8; ++d) o[d] = 0.f;
#pragma unroll
      for (int kk = 0; kk < 8; ++kk) {
        const short8 vv = *(const short8*)&vL[(w*8 + kk)*72 + s8*8];
#pragma unroll
        for (int d = 0; d < 8; ++d) o[d] += pr[kk] * bf2f((u16)vv[d]);
      }
      short8 ov;
#pragma unroll
      for (int d = 0; d < 8; ++d) ov[d] = (short)f2bf(o[d] * inv);
      *(short8*)&qL[tq*72 + s8*8] = ov;    // O into own q-slot
    }
    // scatter offsets (pure ALU; no residual load anymore)
    int offs[8];
#pragma unroll
    for (int mt = 0; mt < 2; ++mt)
#pragma unroll
      for (int r = 0; r < 4; ++r)
        offs[mt*4 + r] = scat(chunk, mt*16 + quad*4 + r) + w*16 + col;
    __syncthreads();                                       // B3: O ready

    // ---- phase 4: proj MFMA (A = O from qL) + scattered store attn+pb ----
    {
      f32x4 c0 = (f32x4){0.f,0.f,0.f,0.f}, c1 = (f32x4){0.f,0.f,0.f,0.f};
      c0 = MFMA(*(const short8*)&qL[(col)*72 + quad*8],         bp[0], c0, 0, 0, 0);
      c0 = MFMA(*(const short8*)&qL[(col)*72 + 32 + quad*8],    bp[1], c0, 0, 0, 0);
      c1 = MFMA(*(const short8*)&qL[(16+col)*72 + quad*8],      bp[0], c1, 0, 0, 0);
      c1 = MFMA(*(const short8*)&qL[(16+col)*72 + 32 + quad*8], bp[1], c1, 0, 0, 0);
#pragma unroll
      for (int r = 0; r < 4; ++r) {
        out[offs[r]]     = c0[r] + pbv;
        out[offs[4 + r]] = c1[r] + pbv;
      }
    }
    // no B4: next chunk's B1 fences phase-4 qL reads vs next phase-2 writes,
    // and aL (written next phase 1) was last read pre-B2 of this chunk.
  }
}

__global__ __launch_bounds__(256, 4)
void attn_kernel(const void* __restrict__ x,
                 const void* __restrict__ n1g, const void* __restrict__ n1b,
                 const void* __restrict__ qkvw, const void* __restrict__ qkvb,
                 const void* __restrict__ rpb,
                 const void* __restrict__ projw, const void* __restrict__ projb,
                 const int* __restrict__ flag, float* __restrict__ out)
{
  __shared__ __align__(16) u16 aL[32*72];   // 4.6 KB
  __shared__ __align__(16) u16 qL[32*72];   // 4.6 KB (q, then O)
  __shared__ __align__(16) u16 kL[32*72];   // 4.6 KB
  __shared__ __align__(16) u16 vL[32*72];   // 4.6 KB  (18.4 KB total)
  if (*flag)
    attn_body<true >(x, n1g, n1b, qkvw, qkvb, rpb, projw, projb, out, aL, qL, kL, vL);
  else
    attn_body<false>(x, n1g, n1b, qkvw, qkvb, rpb, projw, projb, out, aL, qL, kL, vL);
}

// ---------------------------------------------------------------------------
// Kernel 2: y = x(linear) + attnout(linear, from io) ; LN2 + MLP ;
// io = y + mlp. NON-PERSISTENT: one 32-token chunk per block (grid 16384) --
// weight state reloads at most once per block (r10 proved these re-reads are
// L2/L3-hit). PACKED: fragments pre-packed bf16 in ws (no f2bf, 16 coalesced
// short8 loads instead of 128 scalar loads -- cuts ~500 VALU ops/thread).
// ---------------------------------------------------------------------------
template<bool F32, bool PACKED>
__device__ __forceinline__ void mlp_body(
    const void* __restrict__ x, float* __restrict__ io,
    const void* __restrict__ n2g, const void* __restrict__ n2b,
    const void* __restrict__ mw1, const void* __restrict__ mb1,
    const void* __restrict__ mw2, const void* __restrict__ mb2,
    const u16* __restrict__ wsb1, const u16* __restrict__ wsb2,
    u16* __restrict__ aL, u16* __restrict__ hL, float* __restrict__ yL)
{
  const int tid  = threadIdx.x;
  const int w    = tid >> 6, l = tid & 63;
  const int quad = l >> 4,  col = l & 15;
  const int s8   = l >> 3,  cg  = l & 7;
  const int ltok = w*8 + s8;
  const int chunk = blockIdx.x;

  // ---- issue the attnout + x reads immediately (hide under weight loads) ----
  float ao[8], xr[8];
  {
    const float* p = &io[(chunk*32 + ltok)*64 + cg*8];
    const f32x4 a = *(const f32x4*)p;
    const f32x4 c = *(const f32x4*)(p + 4);
    ao[0]=a[0]; ao[1]=a[1]; ao[2]=a[2]; ao[3]=a[3];
    ao[4]=c[0]; ao[5]=c[1]; ao[6]=c[2]; ao[7]=c[3];
  }
  {
    const int base = (chunk*32 + ltok)*64 + cg*8;
    if (F32) {
      const f32x4 a = *(const f32x4*)((const float*)x + base);
      const f32x4 c = *(const f32x4*)((const float*)x + base + 4);
      xr[0]=a[0]; xr[1]=a[1]; xr[2]=a[2]; xr[3]=a[3];
      xr[4]=c[0]; xr[5]=c[1]; xr[6]=c[2]; xr[7]=c[3];
    } else {
      const short8 a = *(const short8*)((const u16*)x + base);
#pragma unroll
      for (int j = 0; j < 8; ++j) xr[j] = bf2f((u16)a[j]);
    }
  }

  float g2v[8], be2v[8];
#pragma unroll
  for (int j = 0; j < 8; ++j) {
    g2v[j]  = ld<F32>(n2g, cg*8 + j);
    be2v[j] = ld<F32>(n2b, cg*8 + j);
  }
  float b1vv[4];
#pragma unroll
  for (int nt = 0; nt < 4; ++nt) b1vv[nt] = ld<F32>(mb1, w*64 + nt*16 + col);
  const float b2vv = ld<F32>(mb2, w*16 + col);

  // W1 fragments (used in phase 1 only)
  short8 b1f[2][4];                  // [kt][nt]
#pragma unroll
  for (int kt = 0; kt < 2; ++kt)
#pragma unroll
    for (int nt = 0; nt < 4; ++nt) {
      if (PACKED) {
        b1f[kt][nt] = *(const short8*)&wsb1[((((w*2 + kt)*4 + nt)*64) + l)*8];
      } else {
        short8 f;
#pragma unroll
        for (int j = 0; j < 8; ++j)
          f[j] = (short)f2bf(ld<F32>(mw1, (kt*32 + quad*8 + j)*256 + w*64 + nt*16 + col));
        b1f[kt][nt] = f;
      }
    }

  // ---- y = x + attnout ; LN2 (token-major group reduce) ; stash y ----
  {
    float yv[8];
#pragma unroll
    for (int j = 0; j < 8; ++j) yv[j] = xr[j] + ao[j];
    float s1 = 0.f, sq = 0.f;
#pragma unroll
    for (int j = 0; j < 8; ++j) { s1 += yv[j]; sq += yv[j]*yv[j]; }
#pragma unroll
    for (int m = 1; m < 8; m <<= 1) {
      s1 += __shfl_xor(s1, m);
      sq += __shfl_xor(sq, m);
    }
    const float mu  = s1 * 0.015625f;
    const float var = sq * 0.015625f - mu * mu;
    const float rs  = rsqrtf(var + 1e-5f);
    short8 av;
#pragma unroll
    for (int j = 0; j < 8; ++j)
      av[j] = (short)f2bf((yv[j] - mu) * rs * g2v[j] + be2v[j]);
    *(short8*)&aL[ltok*72 + cg*8] = av;
    *(f32x4*)&yL[ltok*68 + cg*8]     = (f32x4){yv[0], yv[1], yv[2], yv[3]};
    *(f32x4*)&yL[ltok*68 + cg*8 + 4] = (f32x4){yv[4], yv[5], yv[6], yv[7]};
  }
  __syncthreads();                                       // B1: aL/yL ready

  // ---- phase 1: 32x64 @ 64x256 -> wave's 32x64 slab, GELU -> hL ----
  {
    short8 aF[2][2];
#pragma unroll
    for (int mt = 0; mt < 2; ++mt)
#pragma unroll
      for (int kt = 0; kt < 2; ++kt)
        aF[mt][kt] = *(const short8*)&aL[(mt*16 + col)*72 + kt*32 + quad*8];
#pragma unroll
    for (int nt = 0; nt < 4; ++nt) {
      f32x4 m0 = (f32x4){0.f,0.f,0.f,0.f}, m1 = (f32x4){0.f,0.f,0.f,0.f};
      m0 = MFMA(aF[0][0], b1f[0][nt], m0, 0, 0, 0);
      m0 = MFMA(aF[0][1], b1f[1][nt], m0, 0, 0, 0);
      m1 = MFMA(aF[1][0], b1f[0][nt], m1, 0, 0, 0);
      m1 = MFMA(aF[1][1], b1f[1][nt], m1, 0, 0, 0);
      const float bb = b1vv[nt];
#pragma unroll
      for (int r = 0; r < 4; ++r) {
        {
          const float h = m0[r] + bb;
          const float u = h * (1.5957691216f + 0.0713548162f * (h * h));
          const float e = __expf(u);
          hL[(quad*4 + r)*264 + w*64 + nt*16 + col] =
              f2bf(h - h * __builtin_amdgcn_rcpf(e + 1.f));
        }
        {
          const float h = m1[r] + bb;
          const float u = h * (1.5957691216f + 0.0713548162f * (h * h));
          const float e = __expf(u);
          hL[(16 + quad*4 + r)*264 + w*64 + nt*16 + col] =
              f2bf(h - h * __builtin_amdgcn_rcpf(e + 1.f));
        }
      }
    }
  }

  // W2 fragments (loaded after W1 is dead; used in phase 2 only)
  short8 b2f[8];                     // [kt]
#pragma unroll
  for (int kt = 0; kt < 8; ++kt) {
    if (PACKED) {
      b2f[kt] = *(const short8*)&wsb2[(((w*8 + kt)*64) + l)*8];
    } else {
      short8 f;
#pragma unroll
      for (int j = 0; j < 8; ++j)
        f[j] = (short)f2bf(ld<F32>(mw2, (kt*32 + quad*8 + j)*64 + w*16 + col));
      b2f[kt] = f;
    }
  }
  __syncthreads();                                       // B2: hL ready

  // ---- phase 2: 32x256 @ 256x64 + residual from yL -> io ----
  {
    f32x4 o0 = (f32x4){0.f,0.f,0.f,0.f}, o1 = (f32x4){0.f,0.f,0.f,0.f};
#pragma unroll
    for (int kt = 0; kt < 8; ++kt) {
      o0 = MFMA(*(const short8*)&hL[(col)*264 + kt*32 + quad*8],    b2f[kt], o0, 0, 0, 0);
      o1 = MFMA(*(const short8*)&hL[(16+col)*264 + kt*32 + quad*8], b2f[kt], o1, 0, 0, 0);
    }
#pragma unroll
    for (int r = 0; r < 4; ++r) {
      const int r0 = quad*4 + r, r1 = 16 + quad*4 + r;
      io[(chunk*32 + r0)*64 + w*16 + col] = yL[r0*68 + w*16 + col] + o0[r] + b2vv;
      io[(chunk*32 + r1)*64 + w*16 + col] = yL[r1*68 + w*16 + col] + o1[r] + b2vv;
    }
  }
}

template<bool PACKED>
__global__ __launch_bounds__(256, 4)
void mlp_kernel(const void* __restrict__ x, float* __restrict__ io,
                const void* __restrict__ n2g, const void* __restrict__ n2b,
                const void* __restrict__ mw1, const void* __restrict__ mb1,
                const void* __restrict__ mw2, const void* __restrict__ mb2,
                const u16* __restrict__ wsb1, const u16* __restrict__ wsb2,
                const int* __restrict__ flag)
{
  __shared__ __align__(16) u16   aL[32 * 72];    //  4.6 KB
  __shared__ __align__(16) u16   hL[32 * 264];   // 16.9 KB
  __shared__ __align__(16) float yL[32 * 68];    //  8.7 KB  (30.2 KB total)
  if (*flag)
    mlp_body<true , PACKED>(x, io, n2g, n2b, mw1, mb1, mw2, mb2, wsb1, wsb2, aL, hL, yL);
  else
    mlp_body<false, PACKED>(x, io, n2g, n2b, mw1, mb1, mw2, mb2, wsb1, wsb2, aL, hL, yL);
}

extern "C" void kernel_launch(void* const* d_in, const int* in_sizes, int n_in,
                              void* d_out, int out_size, void* d_ws, size_t ws_size,
                              hipStream_t stream) {
  const void* x     = d_in[0];
  const void* n1g   = d_in[1];
  const void* n1b   = d_in[2];
  const void* qkvw  = d_in[3];
  const void* qkvb  = d_in[4];
  const void* rpb   = d_in[5];
  const void* projw = d_in[6];
  const void* projb = d_in[7];
  const void* n2g   = d_in[8];
  const void* n2b   = d_in[9];
  const void* mw1   = d_in[10];
  const void* mb1   = d_in[11];
  const void* mw2   = d_in[12];
  const void* mb2   = d_in[13];
  float* out = (float*)d_out;
  int* flag  = (int*)d_ws;
  u16* wsb1  = (u16*)((char*)d_ws + 64);
  u16* wsb2  = wsb1 + 16384;
  const bool packed = ws_size >= (size_t)(64 + 2*16384*2);

  detect_kernel<<<dim3(1), dim3(64), 0, stream>>>(x, flag);
  if (packed)
    pack_kernel<<<dim3(16), dim3(256), 0, stream>>>(mw1, mw2, wsb1, wsb2, flag);
  attn_kernel<<<dim3(2048), dim3(256), 0, stream>>>(
      x, n1g, n1b, qkvw, qkvb, rpb, projw, projb, flag, out);
  if (packed)
    mlp_kernel<true ><<<dim3(16384), dim3(256), 0, stream>>>(
        x, out, n2g, n2b, mw1, mb1, mw2, mb2, wsb1, wsb2, flag);
  else
    mlp_kernel<false><<<dim3(16384), dim3(256), 0, stream>>>(
        x, out, n2g, n2b, mw1, mb1, mw2, mb2, wsb1, wsb2, flag);
}